// Round 22
// baseline (437.820 us; speedup 1.0000x reference)
//
#include <hip/hip_runtime.h>

// VQ: B=16, C=D=256, H=64, W=64, K=1024
#define BB 16
#define CC 256
#define HH 64
#define WW 64
#define KK 1024
#define DD 256
#define HW (HH * WW)
#define TAU 0.0625f

typedef __attribute__((ext_vector_type(8))) short bf16x8;
typedef __attribute__((ext_vector_type(4))) float f32x4;

union Frag { bf16x8 v; unsigned int u[4]; };
union U4F  { uint4 u; bf16x8 v; };
__device__ inline bf16x8 asbf(const uint4 x) { U4F c; c.u = x; return c.v; }

__device__ inline void gld16(const void* g, void* l) {
    __builtin_amdgcn_global_load_lds(
        (const __attribute__((address_space(1))) unsigned int*)g,
        (__attribute__((address_space(3))) unsigned int*)l, 16, 0, 0);
}

// trunc-split 8 floats into bf16 hi/lo fragments (x = hi + lo + O(2^-16 x), Sterbenz-exact lo)
__device__ inline void split8r(const float4 a, const float4 b, Frag& hi, Frag& lo) {
    float f[8] = {a.x, a.y, a.z, a.w, b.x, b.y, b.z, b.w};
    #pragma unroll
    for (int p = 0; p < 4; ++p) {
        const unsigned int b0 = __float_as_uint(f[2 * p]), b1 = __float_as_uint(f[2 * p + 1]);
        const unsigned int h0 = b0 & 0xFFFF0000u, h1 = b1 & 0xFFFF0000u;
        const float r0 = f[2 * p]     - __uint_as_float(h0);
        const float r1 = f[2 * p + 1] - __uint_as_float(h1);
        hi.u[p] = (h0 >> 16) | h1;
        lo.u[p] = (__float_as_uint(r0) >> 16) | (__float_as_uint(r1) & 0xFFFF0000u);
    }
}

// Prep: codebook -> bf16 hi/lo in 16x16x32-fragment-linear uint4 layout + ehalf.
// (r16/r18/r21-validated)
__global__ __launch_bounds__(256) void vq_prep_kernel(const float* __restrict__ e,
                                                      float* __restrict__ ehalf,
                                                      uint4* __restrict__ ebt4) {
    const int gt = blockIdx.x * 256 + threadIdx.x;
    const int code = gt >> 3, ks = gt & 7;
    const int ct = code >> 4, col = code & 15;
    const float* src = e + (size_t)code * DD + ks * 32;
    float s = 0.0f;
    #pragma unroll
    for (int kq = 0; kq < 4; ++kq) {
        const float4 va = *reinterpret_cast<const float4*>(src + kq * 8);
        const float4 vb = *reinterpret_cast<const float4*>(src + kq * 8 + 4);
        Frag hi, lo;
        split8r(va, vb, hi, lo);
        const size_t base = (size_t)ct * 1024 + ks * 128 + kq * 16 + col;
        ebt4[base]      = make_uint4(hi.u[0], hi.u[1], hi.u[2], hi.u[3]);
        ebt4[base + 64] = make_uint4(lo.u[0], lo.u[1], lo.u[2], lo.u[3]);
        s += va.x * va.x + va.y * va.y + va.z * va.z + va.w * va.w
           + vb.x * vb.x + vb.y * vb.y + vb.z * vb.z + vb.w * vb.w;
    }
    #pragma unroll
    for (int off = 1; off < 8; off <<= 1) s += __shfl_xor(s, off, 64);
    if (ks == 0) ehalf[code] = 0.5f * s;
}

// ---- shared macros (name-capture: ebt4, wv, lane, ah, al, acch, accl) ----
#define STAGE_HALF(P, KB, BUF) do { \
    _Pragma("unroll") \
    for (int kg_ = 0; kg_ < 4; ++kg_) { \
        const uint4* s_ = ebt4 + (size_t)(P) * 4096 + wv * 1024 + ((KB) + kg_) * 128 + lane; \
        gld16(s_,      &(BUF)[kg_ * 512 + wv * 128]); \
        gld16(s_ + 64, &(BUF)[kg_ * 512 + wv * 128 + 64]); \
    } \
} while (0)

#define COMPUTE_HALF(BUF, KB) do { \
    _Pragma("unroll") \
    for (int kg_ = 0; kg_ < 4; ++kg_) { \
        const uint4* gb_ = (BUF) + kg_ * 512 + lane; \
        uint4 bhu_[4], blu_[4]; \
        _Pragma("unroll") \
        for (int j_ = 0; j_ < 4; ++j_) { \
            bhu_[j_] = gb_[j_ * 128]; \
            blu_[j_] = gb_[j_ * 128 + 64]; \
        } \
        _Pragma("unroll") \
        for (int j_ = 0; j_ < 4; ++j_) \
            acch[j_] = __builtin_amdgcn_mfma_f32_16x16x32_bf16(ah[(KB) + kg_], asbf(bhu_[j_]), acch[j_], 0, 0, 0); \
        _Pragma("unroll") \
        for (int j_ = 0; j_ < 4; ++j_) \
            accl[j_] = __builtin_amdgcn_mfma_f32_16x16x32_bf16(al[(KB) + kg_], asbf(bhu_[j_]), accl[j_], 0, 0, 0); \
        _Pragma("unroll") \
        for (int j_ = 0; j_ < 4; ++j_) \
            acch[j_] = __builtin_amdgcn_mfma_f32_16x16x32_bf16(ah[(KB) + kg_], asbf(blu_[j_]), acch[j_], 0, 0, 0); \
    } \
} while (0)

#define A_LOAD() do { \
    const float* asrc_ = in + (size_t)b * CC * HW + (size_t)h * WW + w2; \
    _Pragma("unroll") \
    for (int ks_ = 0; ks_ < 8; ++ks_) { \
        const int c0_ = ks_ * 32 + lq * 8; \
        float f_[8]; \
        _Pragma("unroll") \
        for (int di_ = 0; di_ < 8; ++di_) f_[di_] = asrc_[(size_t)(c0_ + di_) * HW]; \
        Frag hi_, lo_; \
        split8r(make_float4(f_[0], f_[1], f_[2], f_[3]), \
                make_float4(f_[4], f_[5], f_[6], f_[7]), hi_, lo_); \
        ah[ks_] = hi_.v; al[ks_] = lo_.v; \
    } \
} while (0)

// Main (r21 byte-identical logic): half-pass double buffer, drain+barrier per half.
__global__ __launch_bounds__(256) void vq_mfma_kernel(
    const float* __restrict__ in, const float* __restrict__ emb,
    const float* __restrict__ ehalf, const uint4* __restrict__ ebt4,
    float* __restrict__ out) {

    __shared__ uint4 bb4[2][2048];
    __shared__ float eh_lds[KK];
    __shared__ int   idx_lds[64];
    __shared__ float xs[DD];
    __shared__ int   flags[64];
    __shared__ int   nflag;
    __shared__ float rv[4];
    __shared__ int   ri[4];

    const int tid = threadIdx.x;
    const int bid = blockIdx.x;
    const int b = bid >> 6, h = bid & 63;

    if (tid == 0) nflag = 0;
    for (int k = tid; k < KK; k += 256) eh_lds[k] = ehalf[k];

    const int lane = tid & 63;
    const int wv = tid >> 6;
    const int lr = lane & 15, lq = lane >> 4;
    const int w2 = wv * 16 + lr;

    STAGE_HALF(0, 0, bb4[0]);

    bf16x8 ah[8], al[8];
    A_LOAD();

    float bestv[4], best2[4]; int besti[4];
    #pragma unroll
    for (int r = 0; r < 4; ++r) { bestv[r] = -3.4e38f; best2[r] = -3.4e38f; besti[r] = 0; }

    #pragma unroll 1
    for (int pass = 0; pass < 16; ++pass) {
        f32x4 acch[4], accl[4];
        #pragma unroll
        for (int j = 0; j < 4; ++j) {
            const float nh = -eh_lds[(pass * 4 + j) * 16 + lr];
            acch[j] = (f32x4){nh, nh, nh, nh};
            accl[j] = (f32x4){0.0f, 0.0f, 0.0f, 0.0f};
        }
        asm volatile("s_waitcnt vmcnt(0)" ::: "memory");
        __syncthreads();
        STAGE_HALF(pass, 4, bb4[1]);
        COMPUTE_HALF(bb4[0], 0);
        asm volatile("s_waitcnt vmcnt(0)" ::: "memory");
        __syncthreads();
        if (pass < 15) STAGE_HALF(pass + 1, 0, bb4[0]);
        COMPUTE_HALF(bb4[1], 4);

        #pragma unroll
        for (int j = 0; j < 4; ++j) {
            const int code = (pass * 4 + j) * 16 + lr;
            #pragma unroll
            for (int r = 0; r < 4; ++r) {
                const float v = acch[j][r] + accl[j][r];
                if (v > bestv[r]) { best2[r] = bestv[r]; bestv[r] = v; besti[r] = code; }
                else if (v > best2[r]) best2[r] = v;
            }
        }
    }

    #pragma unroll
    for (int m = 1; m < 16; m <<= 1) {
        #pragma unroll
        for (int r = 0; r < 4; ++r) {
            const float ob = __shfl_xor(bestv[r], m, 64);
            const float o2 = __shfl_xor(best2[r], m, 64);
            const int   oi = __shfl_xor(besti[r], m, 64);
            if (ob > bestv[r] || (ob == bestv[r] && oi < besti[r])) {
                best2[r] = fmaxf(bestv[r], o2); bestv[r] = ob; besti[r] = oi;
            } else {
                best2[r] = fmaxf(best2[r], ob);
            }
        }
    }
    if (lr == 0) {
        #pragma unroll
        for (int r = 0; r < 4; ++r) {
            const int tok = wv * 16 + lq * 4 + r;
            idx_lds[tok] = besti[r];
            if (bestv[r] - best2[r] < TAU) { const int p = atomicAdd(&nflag, 1); flags[p] = tok; }
        }
    }
    __syncthreads();

    const int nf = nflag;
    for (int f = 0; f < nf; ++f) {
        const int wf = flags[f];
        xs[tid] = in[(size_t)(b * CC + tid) * HW + (size_t)h * WW + wf];
        __syncthreads();
        float best = -3.4e38f; int bidx = 0;
        #pragma unroll
        for (int cc = 0; cc < 4; ++cc) {
            const int code = tid * 4 + cc;
            float sc = -eh_lds[code];
            const float* er = emb + (size_t)code * DD;
            for (int d = 0; d < DD; d += 4) {
                sc = fmaf(xs[d + 0], er[d + 0], sc);
                sc = fmaf(xs[d + 1], er[d + 1], sc);
                sc = fmaf(xs[d + 2], er[d + 2], sc);
                sc = fmaf(xs[d + 3], er[d + 3], sc);
            }
            if (sc > best) { best = sc; bidx = code; }
        }
        #pragma unroll
        for (int m2 = 1; m2 < 64; m2 <<= 1) {
            const float ov = __shfl_xor(best, m2, 64);
            const int   oi = __shfl_xor(bidx, m2, 64);
            if (ov > best || (ov == best && oi < bidx)) { best = ov; bidx = oi; }
        }
        if ((tid & 63) == 0) { rv[tid >> 6] = best; ri[tid >> 6] = bidx; }
        __syncthreads();
        if (tid == 0) {
            float fbv = rv[0]; int fbi = ri[0];
            #pragma unroll
            for (int q = 1; q < 4; ++q)
                if (rv[q] > fbv || (rv[q] == fbv && ri[q] < fbi)) { fbv = rv[q]; fbi = ri[q]; }
            idx_lds[wf] = fbi;
        }
        __syncthreads();
    }

    {
        const int w = tid & 63, cs = tid >> 6;
        const float* srcx = in + (size_t)b * CC * HW + (size_t)h * WW + w;
        float* dst = out + (size_t)b * CC * HW + (size_t)h * WW + w;
        const float* erow = emb + (size_t)idx_lds[w] * DD;
        #pragma unroll
        for (int c = cs; c < CC; c += 4) {
            const float x = srcx[(size_t)c * HW];
            const float q = erow[c];
            dst[(size_t)c * HW] = x + (q - x);
        }
    }
}

// ---- P1: compute path only (A-load + ds_read + MFMA + merge), staging loop removed ----
__global__ __launch_bounds__(256) void vq_probe_p1(
    const float* __restrict__ in, const float* __restrict__ ehalf,
    const uint4* __restrict__ ebt4, float* __restrict__ sink) {

    __shared__ uint4 bb4[2][2048];
    __shared__ float eh_lds[KK];
    const int tid = threadIdx.x, bid = blockIdx.x;
    const int b = bid >> 6, h = bid & 63;
    for (int k = tid; k < KK; k += 256) eh_lds[k] = ehalf[k];
    const int lane = tid & 63, wv = tid >> 6;
    const int lr = lane & 15, lq = lane >> 4;
    const int w2 = wv * 16 + lr;

    STAGE_HALF(0, 0, bb4[0]);
    STAGE_HALF(0, 4, bb4[1]);
    bf16x8 ah[8], al[8];
    A_LOAD();
    asm volatile("s_waitcnt vmcnt(0)" ::: "memory");
    __syncthreads();

    float bestv[4], best2[4]; int besti[4];
    #pragma unroll
    for (int r = 0; r < 4; ++r) { bestv[r] = -3.4e38f; best2[r] = -3.4e38f; besti[r] = 0; }

    #pragma unroll 1
    for (int pass = 0; pass < 4; ++pass) {
        unsigned off = 0;
        asm volatile("" : "+v"(off));            // defeat cross-pass ds_read CSE
        const uint4* pb0 = (const uint4*)((const char*)&bb4[0][0] + off);
        const uint4* pb1 = (const uint4*)((const char*)&bb4[1][0] + off);
        f32x4 acch[4], accl[4];
        #pragma unroll
        for (int j = 0; j < 4; ++j) {
            const float nh = -eh_lds[(pass * 4 + j) * 16 + lr];
            acch[j] = (f32x4){nh, nh, nh, nh};
            accl[j] = (f32x4){0.0f, 0.0f, 0.0f, 0.0f};
        }
        COMPUTE_HALF(pb0, 0);
        COMPUTE_HALF(pb1, 4);
        #pragma unroll
        for (int j = 0; j < 4; ++j) {
            const int code = (pass * 4 + j) * 16 + lr;
            #pragma unroll
            for (int r = 0; r < 4; ++r) {
                const float v = acch[j][r] + accl[j][r];
                if (v > bestv[r]) { best2[r] = bestv[r]; bestv[r] = v; besti[r] = code; }
                else if (v > best2[r]) best2[r] = v;
            }
        }
    }
    const float s = bestv[0] + bestv[1] + bestv[2] + bestv[3] + (float)besti[0] + best2[0];
    if (tid == 0) sink[bid] = s;
}

// ---- P2: staging path only (full drain+barrier cadence, XOR consume, no MFMA) ----
__global__ __launch_bounds__(256) void vq_probe_p2(
    const float* __restrict__ in, const float* __restrict__ ehalf,
    const uint4* __restrict__ ebt4, float* __restrict__ sink) {

    __shared__ uint4 bb4[2][2048];
    __shared__ float eh_lds[KK];
    const int tid = threadIdx.x, bid = blockIdx.x;
    const int b = bid >> 6, h = bid & 63;
    for (int k = tid; k < KK; k += 256) eh_lds[k] = ehalf[k];
    const int lane = tid & 63, wv = tid >> 6;
    const int lr = lane & 15, lq = lane >> 4;
    const int w2 = wv * 16 + lr;

    STAGE_HALF(0, 0, bb4[0]);
    bf16x8 ah[8], al[8];
    A_LOAD();

    uint4 xa = make_uint4(0, 0, 0, 0);
    #pragma unroll
    for (int ks = 0; ks < 8; ++ks) { Frag f; f.v = ah[ks]; xa.x ^= f.u[0]; f.v = al[ks]; xa.y ^= f.u[1]; }

    #define XOR_HALF(BUF) do { \
        _Pragma("unroll") \
        for (int kg_ = 0; kg_ < 4; ++kg_) { \
            const uint4* gb_ = (BUF) + kg_ * 512 + lane; \
            _Pragma("unroll") \
            for (int j_ = 0; j_ < 4; ++j_) { \
                const uint4 a_ = gb_[j_ * 128], c_ = gb_[j_ * 128 + 64]; \
                xa.x ^= a_.x ^ c_.x; xa.y ^= a_.y ^ c_.y; \
                xa.z ^= a_.z ^ c_.z; xa.w ^= a_.w ^ c_.w; \
            } \
        } \
    } while (0)

    #pragma unroll 1
    for (int pass = 0; pass < 4; ++pass) {
        asm volatile("s_waitcnt vmcnt(0)" ::: "memory");
        __syncthreads();
        STAGE_HALF(pass, 4, bb4[1]);
        XOR_HALF(bb4[0]);
        asm volatile("s_waitcnt vmcnt(0)" ::: "memory");
        __syncthreads();
        if (pass < 3) STAGE_HALF(pass + 1, 0, bb4[0]);
        XOR_HALF(bb4[1]);
    }
    #undef XOR_HALF
    if (tid == 0) sink[bid] = (float)(xa.x ^ xa.y ^ xa.z ^ xa.w) + eh_lds[bid & 1023];
}

// ---- P3: full loop (staging + MFMA) with ZERO barriers/drains (races; perf only) ----
__global__ __launch_bounds__(256) void vq_probe_p3(
    const float* __restrict__ in, const float* __restrict__ ehalf,
    const uint4* __restrict__ ebt4, float* __restrict__ sink) {

    __shared__ uint4 bb4[2][2048];
    __shared__ float eh_lds[KK];
    const int tid = threadIdx.x, bid = blockIdx.x;
    const int b = bid >> 6, h = bid & 63;
    for (int k = tid; k < KK; k += 256) eh_lds[k] = ehalf[k];
    const int lane = tid & 63, wv = tid >> 6;
    const int lr = lane & 15, lq = lane >> 4;
    const int w2 = wv * 16 + lr;

    STAGE_HALF(0, 0, bb4[0]);
    bf16x8 ah[8], al[8];
    A_LOAD();
    asm volatile("s_waitcnt vmcnt(0)" ::: "memory");
    __syncthreads();

    float bestv[4], best2[4]; int besti[4];
    #pragma unroll
    for (int r = 0; r < 4; ++r) { bestv[r] = -3.4e38f; best2[r] = -3.4e38f; besti[r] = 0; }

    #pragma unroll 1
    for (int pass = 0; pass < 4; ++pass) {
        unsigned off = 0;
        asm volatile("" : "+v"(off));            // defeat cross-pass ds_read CSE
        const uint4* pb0 = (const uint4*)((const char*)&bb4[0][0] + off);
        const uint4* pb1 = (const uint4*)((const char*)&bb4[1][0] + off);
        f32x4 acch[4], accl[4];
        #pragma unroll
        for (int j = 0; j < 4; ++j) {
            const float nh = -eh_lds[(pass * 4 + j) * 16 + lr];
            acch[j] = (f32x4){nh, nh, nh, nh};
            accl[j] = (f32x4){0.0f, 0.0f, 0.0f, 0.0f};
        }
        STAGE_HALF(pass, 4, bb4[1]);
        COMPUTE_HALF(pb0, 0);
        if (pass < 3) STAGE_HALF(pass + 1, 0, bb4[0]);
        COMPUTE_HALF(pb1, 4);
        #pragma unroll
        for (int j = 0; j < 4; ++j) {
            const int code = (pass * 4 + j) * 16 + lr;
            #pragma unroll
            for (int r = 0; r < 4; ++r) {
                const float v = acch[j][r] + accl[j][r];
                if (v > bestv[r]) { best2[r] = bestv[r]; bestv[r] = v; besti[r] = code; }
                else if (v > best2[r]) best2[r] = v;
            }
        }
    }
    const float s = bestv[0] + bestv[1] + bestv[2] + bestv[3] + (float)besti[0] + best2[0];
    if (tid == 0) sink[bid] = s;
}

// ---- fallback path (validated fp32 VALU kernel) if ws is too small ----
__global__ __launch_bounds__(256) void vq_enorm_kernel(const float* __restrict__ e,
                                                       float* __restrict__ ehalf) {
    const int wave = threadIdx.x >> 6;
    const int lane = threadIdx.x & 63;
    const int k = blockIdx.x * 4 + wave;
    const float4 v = *reinterpret_cast<const float4*>(e + (size_t)k * DD + lane * 4);
    float s = v.x * v.x + v.y * v.y + v.z * v.z + v.w * v.w;
    #pragma unroll
    for (int off = 32; off; off >>= 1) s += __shfl_xor(s, off, 64);
    if (lane == 0) ehalf[k] = 0.5f * s;
}

__global__ __launch_bounds__(256) void vq_fallback_kernel(
    const float* __restrict__ in, const float* __restrict__ emb,
    const float* __restrict__ ehalf, float* __restrict__ out) {

    __shared__ float x_lds[64][260];
    __shared__ float red_v[64][16];
    __shared__ int   red_i[64][16];
    __shared__ int   idx_lds[64];

    const int tid = threadIdx.x;
    const int bid = blockIdx.x;
    const int b = bid >> 6, h = bid & 63;
    const int w = tid & 63, cs = tid >> 6;
    {
        const float* src = in + (size_t)b * CC * HW + (size_t)h * WW + w;
        #pragma unroll
        for (int c = cs; c < CC; c += 4) x_lds[w][c] = src[(size_t)c * HW];
    }
    __syncthreads();
    const int i = tid & 15;
    const int j = tid >> 4;
    float best_v[4]; int best_i[4];
    #pragma unroll
    for (int t = 0; t < 4; ++t) { best_v[t] = -3.4e38f; best_i[t] = 0; }
    for (int chunk = 0; chunk < KK; chunk += 128) {
        const int c0 = chunk + j * 8;
        const float* e0 = emb + (size_t)c0 * DD;
        float acc[4][8];
        #pragma unroll
        for (int cj = 0; cj < 8; ++cj) {
            const float nh = -ehalf[c0 + cj];
            #pragma unroll
            for (int t = 0; t < 4; ++t) acc[t][cj] = nh;
        }
        #pragma unroll 2
        for (int d = 0; d < DD; d += 4) {
            float4 xv[4], ev[8];
            #pragma unroll
            for (int t = 0; t < 4; ++t)
                xv[t] = *reinterpret_cast<const float4*>(&x_lds[i + 16 * t][d]);
            #pragma unroll
            for (int cj = 0; cj < 8; ++cj)
                ev[cj] = *reinterpret_cast<const float4*>(e0 + (size_t)cj * DD + d);
            #pragma unroll
            for (int t = 0; t < 4; ++t) {
                #pragma unroll
                for (int cj = 0; cj < 8; ++cj) {
                    float a = acc[t][cj];
                    a = fmaf(xv[t].x, ev[cj].x, a);
                    a = fmaf(xv[t].y, ev[cj].y, a);
                    a = fmaf(xv[t].z, ev[cj].z, a);
                    a = fmaf(xv[t].w, ev[cj].w, a);
                    acc[t][cj] = a;
                }
            }
        }
        #pragma unroll
        for (int cj = 0; cj < 8; ++cj)
            #pragma unroll
            for (int t = 0; t < 4; ++t)
                if (acc[t][cj] > best_v[t]) { best_v[t] = acc[t][cj]; best_i[t] = c0 + cj; }
    }
    #pragma unroll
    for (int t = 0; t < 4; ++t) { red_v[i + 16 * t][j] = best_v[t]; red_i[i + 16 * t][j] = best_i[t]; }
    __syncthreads();
    if (tid < 64) {
        float bv = red_v[tid][0]; int bi = red_i[tid][0];
        #pragma unroll
        for (int jj = 1; jj < 16; ++jj) {
            const float v = red_v[tid][jj]; const int id = red_i[tid][jj];
            if (v > bv || (v == bv && id < bi)) { bv = v; bi = id; }
        }
        idx_lds[tid] = bi;
    }
    __syncthreads();
    {
        float* dst = out + (size_t)b * CC * HW + (size_t)h * WW + w;
        const float* erow = emb + (size_t)idx_lds[w] * DD;
        #pragma unroll
        for (int c = cs; c < CC; c += 4) {
            const float x = x_lds[w][c];
            const float q = erow[c];
            dst[(size_t)c * HW] = x + (q - x);
        }
    }
}

extern "C" void kernel_launch(void* const* d_in, const int* in_sizes, int n_in,
                              void* d_out, int out_size, void* d_ws, size_t ws_size,
                              hipStream_t stream) {
    const float* in  = (const float*)d_in[0];
    const float* emb = (const float*)d_in[1];
    float* out = (float*)d_out;
    char* ws = (char*)d_ws;

    float* ehalf = (float*)ws;                                 // 4 KiB
    const size_t OFF_EBT  = 4096;
    const size_t OFF_SINK = OFF_EBT + (size_t)KK * DD * 2 * 2; // +1 MiB
    const size_t NEED     = OFF_EBT + (size_t)KK * DD * 2 * 2;
    const size_t NEED2    = OFF_SINK + 4096;

    if (ws_size < NEED) {
        vq_enorm_kernel<<<KK / 4, 256, 0, stream>>>(emb, ehalf);
        vq_fallback_kernel<<<BB * HH, 256, 0, stream>>>(in, emb, ehalf, out);
        return;
    }
    uint4* ebt4 = (uint4*)(ws + OFF_EBT);

    vq_prep_kernel<<<32, 256, 0, stream>>>(emb, ehalf, ebt4);
    vq_mfma_kernel<<<BB * HH, 256, 0, stream>>>(in, emb, ehalf, ebt4, out);

    if (ws_size >= NEED2) {   // ablation probes (write only to ws sink; output untouched)
        float* sink = (float*)(ws + OFF_SINK);
        vq_probe_p1<<<BB * HH, 256, 0, stream>>>(in, ehalf, ebt4, sink);
        vq_probe_p2<<<BB * HH, 256, 0, stream>>>(in, ehalf, ebt4, sink);
        vq_probe_p3<<<BB * HH, 256, 0, stream>>>(in, ehalf, ebt4, sink);
    }
}

// Round 23
// 388.059 us; speedup vs baseline: 1.1282x; 1.1282x over previous
//
#include <hip/hip_runtime.h>

// VQ: B=16, C=D=256, H=64, W=64, K=1024
#define BB 16
#define CC 256
#define HH 64
#define WW 64
#define KK 1024
#define DD 256
#define HW (HH * WW)
#define TAU 0.0625f

typedef __attribute__((ext_vector_type(8))) short bf16x8;
typedef __attribute__((ext_vector_type(4))) float f32x4;

union Frag { bf16x8 v; unsigned int u[4]; };
union U4F  { uint4 u; bf16x8 v; };
__device__ inline bf16x8 asbf(const uint4 x) { U4F c; c.u = x; return c.v; }

__device__ inline void gld16(const void* g, void* l) {
    __builtin_amdgcn_global_load_lds(
        (const __attribute__((address_space(1))) unsigned int*)g,
        (__attribute__((address_space(3))) unsigned int*)l, 16, 0, 0);
}

// trunc-split 8 floats into bf16 hi/lo fragments (x = hi + lo + O(2^-16 x), Sterbenz-exact lo)
__device__ inline void split8r(const float4 a, const float4 b, Frag& hi, Frag& lo) {
    float f[8] = {a.x, a.y, a.z, a.w, b.x, b.y, b.z, b.w};
    #pragma unroll
    for (int p = 0; p < 4; ++p) {
        const unsigned int b0 = __float_as_uint(f[2 * p]), b1 = __float_as_uint(f[2 * p + 1]);
        const unsigned int h0 = b0 & 0xFFFF0000u, h1 = b1 & 0xFFFF0000u;
        const float r0 = f[2 * p]     - __uint_as_float(h0);
        const float r1 = f[2 * p + 1] - __uint_as_float(h1);
        hi.u[p] = (h0 >> 16) | h1;
        lo.u[p] = (__float_as_uint(r0) >> 16) | (__float_as_uint(r1) & 0xFFFF0000u);
    }
}

// Prep: codebook -> bf16 hi/lo in 16x16x32-fragment-linear uint4 layout + ehalf.
// (r16/r18/r21-validated)  ebt4[ct*1024 + ks*128 + term*64 + lane], lane = kq*16 + col.
__global__ __launch_bounds__(256) void vq_prep_kernel(const float* __restrict__ e,
                                                      float* __restrict__ ehalf,
                                                      uint4* __restrict__ ebt4) {
    const int gt = blockIdx.x * 256 + threadIdx.x;
    const int code = gt >> 3, ks = gt & 7;
    const int ct = code >> 4, col = code & 15;
    const float* src = e + (size_t)code * DD + ks * 32;
    float s = 0.0f;
    #pragma unroll
    for (int kq = 0; kq < 4; ++kq) {
        const float4 va = *reinterpret_cast<const float4*>(src + kq * 8);
        const float4 vb = *reinterpret_cast<const float4*>(src + kq * 8 + 4);
        Frag hi, lo;
        split8r(va, vb, hi, lo);
        const size_t base = (size_t)ct * 1024 + ks * 128 + kq * 16 + col;
        ebt4[base]      = make_uint4(hi.u[0], hi.u[1], hi.u[2], hi.u[3]);
        ebt4[base + 64] = make_uint4(lo.u[0], lo.u[1], lo.u[2], lo.u[3]);
        s += va.x * va.x + va.y * va.y + va.z * va.z + va.w * va.w
           + vb.x * vb.x + vb.y * vb.y + vb.z * vb.z + vb.w * vb.w;
    }
    #pragma unroll
    for (int off = 1; off < 8; off <<= 1) s += __shfl_xor(s, off, 64);
    if (ks == 0) ehalf[code] = 0.5f * s;
}

// stage (8-wave roles): wave wv stages frag j=wv&3, term=wv>>2 for 4 granules
#define STAGE_HALF(P, KB, BUF) do { \
    const int js_ = wv & 3, ts_ = wv >> 2; \
    _Pragma("unroll") \
    for (int kg_ = 0; kg_ < 4; ++kg_) { \
        const uint4* s_ = ebt4 + (size_t)(P) * 4096 + js_ * 1024 + ((KB) + kg_) * 128 + ts_ * 64 + lane; \
        gld16(s_, &(BUF)[kg_ * 512 + js_ * 128 + ts_ * 64]); \
    } \
} while (0)

// consume 4 granules from BUF with A-frag base KB (r21-validated)
#define COMPUTE_HALF(BUF, KB) do { \
    _Pragma("unroll") \
    for (int kg_ = 0; kg_ < 4; ++kg_) { \
        const uint4* gb_ = (BUF) + kg_ * 512 + lane; \
        uint4 bhu_[4], blu_[4]; \
        _Pragma("unroll") \
        for (int j_ = 0; j_ < 4; ++j_) { \
            bhu_[j_] = gb_[j_ * 128]; \
            blu_[j_] = gb_[j_ * 128 + 64]; \
        } \
        _Pragma("unroll") \
        for (int j_ = 0; j_ < 4; ++j_) \
            acch[j_] = __builtin_amdgcn_mfma_f32_16x16x32_bf16(ah[(KB) + kg_], asbf(bhu_[j_]), acch[j_], 0, 0, 0); \
        _Pragma("unroll") \
        for (int j_ = 0; j_ < 4; ++j_) \
            accl[j_] = __builtin_amdgcn_mfma_f32_16x16x32_bf16(al[(KB) + kg_], asbf(bhu_[j_]), accl[j_], 0, 0, 0); \
        _Pragma("unroll") \
        for (int j_ = 0; j_ < 4; ++j_) \
            acch[j_] = __builtin_amdgcn_mfma_f32_16x16x32_bf16(ah[(KB) + kg_], asbf(blu_[j_]), acch[j_], 0, 0, 0); \
    } \
} while (0)

// Main: one block per TWO (b,h) rows = 128 tokens; 8 waves (512 thr).
// Wave wv: tokens (wv&3)*16..+15 of row wv>>2, ALL 1024 codes.
// r21-validated half-pass double buffer; drain+barrier per half.
__global__ __launch_bounds__(512) void vq_mfma_kernel(
    const float* __restrict__ in, const float* __restrict__ emb,
    const float* __restrict__ ehalf, const uint4* __restrict__ ebt4,
    float* __restrict__ out) {

    __shared__ uint4 bb4[2][2048];      // 2 x 32 KB half-pass buffers
    __shared__ float eh_lds[KK];
    __shared__ int   idx_lds[128];
    __shared__ float xs[DD];
    __shared__ int   flags[128];
    __shared__ int   nflag;
    __shared__ float rv[8];
    __shared__ int   ri[8];

    const int tid = threadIdx.x;
    const int bid = blockIdx.x;

    if (tid == 0) nflag = 0;
    for (int k = tid; k < KK; k += 512) eh_lds[k] = ehalf[k];

    const int lane = tid & 63;
    const int wv = tid >> 6;            // 8 waves
    const int lr = lane & 15, lq = lane >> 4;

    STAGE_HALF(0, 0, bb4[0]);           // pass-0 first half; hides under A-load

    // ---- A fragments: this wave's 16 tokens of row wv>>2 (r16-validated layout) ----
    bf16x8 ah[8], al[8];
    {
        const int bhA = bid * 2 + (wv >> 2);
        const int bA = bhA >> 6, hA = bhA & 63;
        const int w2 = (wv & 3) * 16 + lr;
        const float* asrc = in + (size_t)bA * CC * HW + (size_t)hA * WW + w2;
        #pragma unroll
        for (int ks = 0; ks < 8; ++ks) {
            const int c0 = ks * 32 + lq * 8;
            float f[8];
            #pragma unroll
            for (int di = 0; di < 8; ++di) f[di] = asrc[(size_t)(c0 + di) * HW];
            Frag hi, lo;
            split8r(make_float4(f[0], f[1], f[2], f[3]),
                    make_float4(f[4], f[5], f[6], f[7]), hi, lo);
            ah[ks] = hi.v; al[ks] = lo.v;
        }
    }

    float bestv[4], best2[4]; int besti[4];
    #pragma unroll
    for (int r = 0; r < 4; ++r) { bestv[r] = -3.4e38f; best2[r] = -3.4e38f; besti[r] = 0; }

    // ---- K-loop: 16 passes x 2 halves; drain+barrier per half (r21 invariant) ----
    #pragma unroll 1
    for (int pass = 0; pass < 16; ++pass) {
        f32x4 acch[4], accl[4];
        #pragma unroll
        for (int j = 0; j < 4; ++j) {
            const float nh = -eh_lds[(pass * 4 + j) * 16 + lr];
            acch[j] = (f32x4){nh, nh, nh, nh};
            accl[j] = (f32x4){0.0f, 0.0f, 0.0f, 0.0f};
        }
        asm volatile("s_waitcnt vmcnt(0)" ::: "memory");
        __syncthreads();
        STAGE_HALF(pass, 4, bb4[1]);
        COMPUTE_HALF(bb4[0], 0);
        asm volatile("s_waitcnt vmcnt(0)" ::: "memory");
        __syncthreads();
        if (pass < 15) STAGE_HALF(pass + 1, 0, bb4[0]);
        COMPUTE_HALF(bb4[1], 4);

        #pragma unroll
        for (int j = 0; j < 4; ++j) {
            const int code = (pass * 4 + j) * 16 + lr;     // ascending per lane
            #pragma unroll
            for (int r = 0; r < 4; ++r) {
                const float v = acch[j][r] + accl[j][r];
                if (v > bestv[r]) { best2[r] = bestv[r]; bestv[r] = v; besti[r] = code; }
                else if (v > best2[r]) best2[r] = v;
            }
        }
    }

    // ---- butterfly across the 16 code-columns (r16-validated) ----
    #pragma unroll
    for (int m = 1; m < 16; m <<= 1) {
        #pragma unroll
        for (int r = 0; r < 4; ++r) {
            const float ob = __shfl_xor(bestv[r], m, 64);
            const float o2 = __shfl_xor(best2[r], m, 64);
            const int   oi = __shfl_xor(besti[r], m, 64);
            if (ob > bestv[r] || (ob == bestv[r] && oi < besti[r])) {
                best2[r] = fmaxf(bestv[r], o2); bestv[r] = ob; besti[r] = oi;
            } else {
                best2[r] = fmaxf(best2[r], ob);
            }
        }
    }
    if (lr == 0) {
        #pragma unroll
        for (int r = 0; r < 4; ++r) {
            const int tok = (wv >> 2) * 64 + (wv & 3) * 16 + lq * 4 + r;  // C/D row = lq*4+r
            idx_lds[tok] = besti[r];
            if (bestv[r] - best2[r] < TAU) { const int p = atomicAdd(&nflag, 1); flags[p] = tok; }
        }
    }
    __syncthreads();

    // ---- inline rescue: exact fp32 recompute for flagged tokens (2 codes/thread) ----
    const int nf = nflag;
    for (int f = 0; f < nf; ++f) {
        const int ft = flags[f];
        const int row = ft >> 6, wl = ft & 63;
        const int bh2 = bid * 2 + row;
        const int b2 = bh2 >> 6, h2 = bh2 & 63;
        if (tid < CC) xs[tid] = in[(size_t)(b2 * CC + tid) * HW + (size_t)h2 * WW + wl];
        __syncthreads();
        float best = -3.4e38f; int bidx = 0;
        #pragma unroll
        for (int cc = 0; cc < 2; ++cc) {
            const int code = tid * 2 + cc;                 // ascending per thread
            float sc = -eh_lds[code];
            const float* er = emb + (size_t)code * DD;
            for (int d = 0; d < DD; d += 4) {
                sc = fmaf(xs[d + 0], er[d + 0], sc);
                sc = fmaf(xs[d + 1], er[d + 1], sc);
                sc = fmaf(xs[d + 2], er[d + 2], sc);
                sc = fmaf(xs[d + 3], er[d + 3], sc);
            }
            if (sc > best) { best = sc; bidx = code; }
        }
        #pragma unroll
        for (int m2 = 1; m2 < 64; m2 <<= 1) {
            const float ov = __shfl_xor(best, m2, 64);
            const int   oi = __shfl_xor(bidx, m2, 64);
            if (ov > best || (ov == best && oi < bidx)) { best = ov; bidx = oi; }
        }
        if ((tid & 63) == 0) { rv[tid >> 6] = best; ri[tid >> 6] = bidx; }
        __syncthreads();
        if (tid == 0) {
            float fbv = rv[0]; int fbi = ri[0];
            #pragma unroll
            for (int q = 1; q < 8; ++q)
                if (rv[q] > fbv || (rv[q] == fbv && ri[q] < fbi)) { fbv = rv[q]; fbi = ri[q]; }
            idx_lds[ft] = fbi;
        }
        __syncthreads();
    }

    // ---- epilogue: out = x + (q - x); 128 tokens x 256 channels, coalesced over w ----
    {
        const int w = tid & 63;
        const int sel = tid >> 6;          // 0..7
        const int row = sel & 1, cs = sel >> 1;   // cs 0..3
        const int bh2 = bid * 2 + row;
        const int b2 = bh2 >> 6, h2 = bh2 & 63;
        const float* srcx = in + (size_t)b2 * CC * HW + (size_t)h2 * WW + w;
        float* dst = out + (size_t)b2 * CC * HW + (size_t)h2 * WW + w;
        const float* erow = emb + (size_t)idx_lds[row * 64 + w] * DD;
        #pragma unroll
        for (int c = cs; c < CC; c += 4) {
            const float x = srcx[(size_t)c * HW];
            const float q = erow[c];
            dst[(size_t)c * HW] = x + (q - x);
        }
    }
}

// ---- fallback path (validated fp32 VALU kernel) if ws is too small ----
__global__ __launch_bounds__(256) void vq_enorm_kernel(const float* __restrict__ e,
                                                       float* __restrict__ ehalf) {
    const int wave = threadIdx.x >> 6;
    const int lane = threadIdx.x & 63;
    const int k = blockIdx.x * 4 + wave;
    const float4 v = *reinterpret_cast<const float4*>(e + (size_t)k * DD + lane * 4);
    float s = v.x * v.x + v.y * v.y + v.z * v.z + v.w * v.w;
    #pragma unroll
    for (int off = 32; off; off >>= 1) s += __shfl_xor(s, off, 64);
    if (lane == 0) ehalf[k] = 0.5f * s;
}

__global__ __launch_bounds__(256) void vq_fallback_kernel(
    const float* __restrict__ in, const float* __restrict__ emb,
    const float* __restrict__ ehalf, float* __restrict__ out) {

    __shared__ float x_lds[64][260];
    __shared__ float red_v[64][16];
    __shared__ int   red_i[64][16];
    __shared__ int   idx_lds[64];

    const int tid = threadIdx.x;
    const int bid = blockIdx.x;
    const int b = bid >> 6, h = bid & 63;
    const int w = tid & 63, cs = tid >> 6;
    {
        const float* src = in + (size_t)b * CC * HW + (size_t)h * WW + w;
        #pragma unroll
        for (int c = cs; c < CC; c += 4) x_lds[w][c] = src[(size_t)c * HW];
    }
    __syncthreads();
    const int i = tid & 15;
    const int j = tid >> 4;
    float best_v[4]; int best_i[4];
    #pragma unroll
    for (int t = 0; t < 4; ++t) { best_v[t] = -3.4e38f; best_i[t] = 0; }
    for (int chunk = 0; chunk < KK; chunk += 128) {
        const int c0 = chunk + j * 8;
        const float* e0 = emb + (size_t)c0 * DD;
        float acc[4][8];
        #pragma unroll
        for (int cj = 0; cj < 8; ++cj) {
            const float nh = -ehalf[c0 + cj];
            #pragma unroll
            for (int t = 0; t < 4; ++t) acc[t][cj] = nh;
        }
        #pragma unroll 2
        for (int d = 0; d < DD; d += 4) {
            float4 xv[4], ev[8];
            #pragma unroll
            for (int t = 0; t < 4; ++t)
                xv[t] = *reinterpret_cast<const float4*>(&x_lds[i + 16 * t][d]);
            #pragma unroll
            for (int cj = 0; cj < 8; ++cj)
                ev[cj] = *reinterpret_cast<const float4*>(e0 + (size_t)cj * DD + d);
            #pragma unroll
            for (int t = 0; t < 4; ++t) {
                #pragma unroll
                for (int cj = 0; cj < 8; ++cj) {
                    float a = acc[t][cj];
                    a = fmaf(xv[t].x, ev[cj].x, a);
                    a = fmaf(xv[t].y, ev[cj].y, a);
                    a = fmaf(xv[t].z, ev[cj].z, a);
                    a = fmaf(xv[t].w, ev[cj].w, a);
                    acc[t][cj] = a;
                }
            }
        }
        #pragma unroll
        for (int cj = 0; cj < 8; ++cj)
            #pragma unroll
            for (int t = 0; t < 4; ++t)
                if (acc[t][cj] > best_v[t]) { best_v[t] = acc[t][cj]; best_i[t] = c0 + cj; }
    }
    #pragma unroll
    for (int t = 0; t < 4; ++t) { red_v[i + 16 * t][j] = best_v[t]; red_i[i + 16 * t][j] = best_i[t]; }
    __syncthreads();
    if (tid < 64) {
        float bv = red_v[tid][0]; int bi = red_i[tid][0];
        #pragma unroll
        for (int jj = 1; jj < 16; ++jj) {
            const float v = red_v[tid][jj]; const int id = red_i[tid][jj];
            if (v > bv || (v == bv && id < bi)) { bv = v; bi = id; }
        }
        idx_lds[tid] = bi;
    }
    __syncthreads();
    {
        float* dst = out + (size_t)b * CC * HW + (size_t)h * WW + w;
        const float* erow = emb + (size_t)idx_lds[w] * DD;
        #pragma unroll
        for (int c = cs; c < CC; c += 4) {
            const float x = x_lds[w][c];
            const float q = erow[c];
            dst[(size_t)c * HW] = x + (q - x);
        }
    }
}

extern "C" void kernel_launch(void* const* d_in, const int* in_sizes, int n_in,
                              void* d_out, int out_size, void* d_ws, size_t ws_size,
                              hipStream_t stream) {
    const float* in  = (const float*)d_in[0];
    const float* emb = (const float*)d_in[1];
    float* out = (float*)d_out;
    char* ws = (char*)d_ws;

    float* ehalf = (float*)ws;                                 // 4 KiB
    const size_t OFF_EBT = 4096;
    const size_t NEED = OFF_EBT + (size_t)KK * DD * 2 * 2;     // + 1 MiB

    if (ws_size < NEED) {
        vq_enorm_kernel<<<KK / 4, 256, 0, stream>>>(emb, ehalf);
        vq_fallback_kernel<<<BB * HH, 256, 0, stream>>>(in, emb, ehalf, out);
        return;
    }
    uint4* ebt4 = (uint4*)(ws + OFF_EBT);

    vq_prep_kernel<<<32, 256, 0, stream>>>(emb, ehalf, ebt4);
    vq_mfma_kernel<<<BB * HH / 2, 512, 0, stream>>>(in, emb, ehalf, ebt4, out);
}

// Round 24
// 378.741 us; speedup vs baseline: 1.1560x; 1.0246x over previous
//
#include <hip/hip_runtime.h>

// VQ: B=16, C=D=256, H=64, W=64, K=1024
#define BB 16
#define CC 256
#define HH 64
#define WW 64
#define KK 1024
#define DD 256
#define HW (HH * WW)
#define TAU 0.0625f

typedef __attribute__((ext_vector_type(8))) short bf16x8;
typedef __attribute__((ext_vector_type(4))) float f32x4;

union Frag { bf16x8 v; unsigned int u[4]; };
union U4F  { uint4 u; bf16x8 v; };
__device__ inline bf16x8 asbf(const uint4 x) { U4F c; c.u = x; return c.v; }

// trunc-split 8 floats into bf16 hi/lo fragments (x = hi + lo + O(2^-16 x), Sterbenz-exact lo)
__device__ inline void split8r(const float4 a, const float4 b, Frag& hi, Frag& lo) {
    float f[8] = {a.x, a.y, a.z, a.w, b.x, b.y, b.z, b.w};
    #pragma unroll
    for (int p = 0; p < 4; ++p) {
        const unsigned int b0 = __float_as_uint(f[2 * p]), b1 = __float_as_uint(f[2 * p + 1]);
        const unsigned int h0 = b0 & 0xFFFF0000u, h1 = b1 & 0xFFFF0000u;
        const float r0 = f[2 * p]     - __uint_as_float(h0);
        const float r1 = f[2 * p + 1] - __uint_as_float(h1);
        hi.u[p] = (h0 >> 16) | h1;
        lo.u[p] = (__float_as_uint(r0) >> 16) | (__float_as_uint(r1) & 0xFFFF0000u);
    }
}

// Prep: codebook -> bf16 hi/lo in 16x16x32-fragment-linear uint4 layout + ehalf.
// (r16/r18/r21-validated)  ebt4[ct*1024 + ks*128 + term*64 + lane], lane = kq*16 + col.
__global__ __launch_bounds__(256) void vq_prep_kernel(const float* __restrict__ e,
                                                      float* __restrict__ ehalf,
                                                      uint4* __restrict__ ebt4) {
    const int gt = blockIdx.x * 256 + threadIdx.x;
    const int code = gt >> 3, ks = gt & 7;
    const int ct = code >> 4, col = code & 15;
    const float* src = e + (size_t)code * DD + ks * 32;
    float s = 0.0f;
    #pragma unroll
    for (int kq = 0; kq < 4; ++kq) {
        const float4 va = *reinterpret_cast<const float4*>(src + kq * 8);
        const float4 vb = *reinterpret_cast<const float4*>(src + kq * 8 + 4);
        Frag hi, lo;
        split8r(va, vb, hi, lo);
        const size_t base = (size_t)ct * 1024 + ks * 128 + kq * 16 + col;
        ebt4[base]      = make_uint4(hi.u[0], hi.u[1], hi.u[2], hi.u[3]);
        ebt4[base + 64] = make_uint4(lo.u[0], lo.u[1], lo.u[2], lo.u[3]);
        s += va.x * va.x + va.y * va.y + va.z * va.z + va.w * va.w
           + vb.x * vb.x + vb.y * vb.y + vb.z * vb.z + vb.w * vb.w;
    }
    #pragma unroll
    for (int off = 1; off < 8; off <<= 1) s += __shfl_xor(s, off, 64);
    if (ks == 0) ehalf[code] = 0.5f * s;
}

// Main: one block per (b,h) = 64 tokens; 4 waves, NO barriers in the K-loop.
// Wave (mg = wv>>1, ng = wv&1): two 16-token A-tiles (mg*32, mg*32+16), codes
// ng*512..+511 streamed DIRECT from L2 (fragment-linear, 1 KB coalesced loads,
// depth-1 register prefetch). Cross-wave merge of the two ng halves at the end.
__global__ __launch_bounds__(256) void vq_mfma_kernel(
    const float* __restrict__ in, const float* __restrict__ emb,
    const float* __restrict__ ehalf, const uint4* __restrict__ ebt4,
    float* __restrict__ out) {

    __shared__ float eh_lds[KK];
    __shared__ float mv[64][2], m2l[64][2];
    __shared__ int   mi[64][2];
    __shared__ int   idx_lds[64];
    __shared__ float xs[DD];
    __shared__ int   flags[64];
    __shared__ int   nflag;
    __shared__ float rv[4];
    __shared__ int   ri[4];

    const int tid = threadIdx.x;
    const int bid = blockIdx.x;
    const int b = bid >> 6, h = bid & 63;

    if (tid == 0) nflag = 0;
    for (int k = tid; k < KK; k += 256) eh_lds[k] = ehalf[k];

    const int lane = tid & 63;
    const int wv = tid >> 6;
    const int mg = wv >> 1, ng = wv & 1;
    const int lr = lane & 15, lq = lane >> 4;

    // ---- A fragments: two tiles (tokens mg*32+lr, mg*32+16+lr), 128 VGPR ----
    bf16x8 ah0[8], al0[8], ah1[8], al1[8];
    {
        const float* base = in + (size_t)b * CC * HW + (size_t)h * WW;
        const float* s0 = base + mg * 32 + lr;
        const float* s1 = s0 + 16;
        #pragma unroll
        for (int ks = 0; ks < 8; ++ks) {
            const int c0 = ks * 32 + lq * 8;
            float f0[8], f1[8];
            #pragma unroll
            for (int di = 0; di < 8; ++di) {
                f0[di] = s0[(size_t)(c0 + di) * HW];
                f1[di] = s1[(size_t)(c0 + di) * HW];
            }
            Frag hi, lo;
            split8r(make_float4(f0[0], f0[1], f0[2], f0[3]),
                    make_float4(f0[4], f0[5], f0[6], f0[7]), hi, lo);
            ah0[ks] = hi.v; al0[ks] = lo.v;
            split8r(make_float4(f1[0], f1[1], f1[2], f1[3]),
                    make_float4(f1[4], f1[5], f1[6], f1[7]), hi, lo);
            ah1[ks] = hi.v; al1[ks] = lo.v;
        }
    }
    __syncthreads();   // eh_lds ready (only barrier before the final merge)

    float b0v[4], b02[4], b1v[4], b12[4];
    int   b0i[4], b1i[4];
    #pragma unroll
    for (int r = 0; r < 4; ++r) {
        b0v[r] = -3.4e38f; b02[r] = -3.4e38f; b0i[r] = 0;
        b1v[r] = -3.4e38f; b12[r] = -3.4e38f; b1i[r] = 0;
    }

    // ---- K-loop: 16 passes x 2 cts; direct-L2 B stream, depth-1 prefetch, NO barriers ----
    #pragma unroll 1
    for (int pc = 0; pc < 16; ++pc) {
        const int ct0 = ng * 32 + pc * 2;
        const uint4* p0 = ebt4 + (size_t)ct0 * 1024 + lane;
        const uint4* p1 = p0 + 1024;
        f32x4 a0h[2], a0l[2], a1h[2], a1l[2];
        #pragma unroll
        for (int c = 0; c < 2; ++c) {
            const float nh = -eh_lds[(ct0 + c) * 16 + lr];
            a0h[c] = (f32x4){nh, nh, nh, nh};
            a0l[c] = (f32x4){0.0f, 0.0f, 0.0f, 0.0f};
            a1h[c] = (f32x4){nh, nh, nh, nh};
            a1l[c] = (f32x4){0.0f, 0.0f, 0.0f, 0.0f};
        }
        uint4 c0h = p0[0], c0l = p0[64], c1h = p1[0], c1l = p1[64];
        #pragma unroll
        for (int ks = 0; ks < 8; ++ks) {
            uint4 n0h, n0l, n1h, n1l;
            if (ks < 7) {
                n0h = p0[(ks + 1) * 128];      n0l = p0[(ks + 1) * 128 + 64];
                n1h = p1[(ks + 1) * 128];      n1l = p1[(ks + 1) * 128 + 64];
            }
            const bf16x8 bh0 = asbf(c0h), bl0 = asbf(c0l);
            const bf16x8 bh1 = asbf(c1h), bl1 = asbf(c1l);
            a0h[0] = __builtin_amdgcn_mfma_f32_16x16x32_bf16(ah0[ks], bh0, a0h[0], 0, 0, 0);
            a1h[0] = __builtin_amdgcn_mfma_f32_16x16x32_bf16(ah1[ks], bh0, a1h[0], 0, 0, 0);
            a0h[1] = __builtin_amdgcn_mfma_f32_16x16x32_bf16(ah0[ks], bh1, a0h[1], 0, 0, 0);
            a1h[1] = __builtin_amdgcn_mfma_f32_16x16x32_bf16(ah1[ks], bh1, a1h[1], 0, 0, 0);
            a0l[0] = __builtin_amdgcn_mfma_f32_16x16x32_bf16(al0[ks], bh0, a0l[0], 0, 0, 0);
            a1l[0] = __builtin_amdgcn_mfma_f32_16x16x32_bf16(al1[ks], bh0, a1l[0], 0, 0, 0);
            a0l[1] = __builtin_amdgcn_mfma_f32_16x16x32_bf16(al0[ks], bh1, a0l[1], 0, 0, 0);
            a1l[1] = __builtin_amdgcn_mfma_f32_16x16x32_bf16(al1[ks], bh1, a1l[1], 0, 0, 0);
            a0h[0] = __builtin_amdgcn_mfma_f32_16x16x32_bf16(ah0[ks], bl0, a0h[0], 0, 0, 0);
            a1h[0] = __builtin_amdgcn_mfma_f32_16x16x32_bf16(ah1[ks], bl0, a1h[0], 0, 0, 0);
            a0h[1] = __builtin_amdgcn_mfma_f32_16x16x32_bf16(ah0[ks], bl1, a0h[1], 0, 0, 0);
            a1h[1] = __builtin_amdgcn_mfma_f32_16x16x32_bf16(ah1[ks], bl1, a1h[1], 0, 0, 0);
            if (ks < 7) { c0h = n0h; c0l = n0l; c1h = n1h; c1l = n1l; }
        }
        #pragma unroll
        for (int c = 0; c < 2; ++c) {
            const int code = (ct0 + c) * 16 + lr;          // ascending per lane
            #pragma unroll
            for (int r = 0; r < 4; ++r) {
                const float v0 = a0h[c][r] + a0l[c][r];
                if (v0 > b0v[r]) { b02[r] = b0v[r]; b0v[r] = v0; b0i[r] = code; }
                else if (v0 > b02[r]) b02[r] = v0;
                const float v1 = a1h[c][r] + a1l[c][r];
                if (v1 > b1v[r]) { b12[r] = b1v[r]; b1v[r] = v1; b1i[r] = code; }
                else if (v1 > b12[r]) b12[r] = v1;
            }
        }
    }

    // ---- butterfly across the 16 code-columns, both tiles (r16-validated) ----
    #pragma unroll
    for (int m = 1; m < 16; m <<= 1) {
        #pragma unroll
        for (int r = 0; r < 4; ++r) {
            {
                const float ob = __shfl_xor(b0v[r], m, 64);
                const float o2 = __shfl_xor(b02[r], m, 64);
                const int   oi = __shfl_xor(b0i[r], m, 64);
                if (ob > b0v[r] || (ob == b0v[r] && oi < b0i[r])) {
                    b02[r] = fmaxf(b0v[r], o2); b0v[r] = ob; b0i[r] = oi;
                } else {
                    b02[r] = fmaxf(b02[r], ob);
                }
            }
            {
                const float ob = __shfl_xor(b1v[r], m, 64);
                const float o2 = __shfl_xor(b12[r], m, 64);
                const int   oi = __shfl_xor(b1i[r], m, 64);
                if (ob > b1v[r] || (ob == b1v[r] && oi < b1i[r])) {
                    b12[r] = fmaxf(b1v[r], o2); b1v[r] = ob; b1i[r] = oi;
                } else {
                    b12[r] = fmaxf(b12[r], ob);
                }
            }
        }
    }
    if (lr == 0) {
        #pragma unroll
        for (int r = 0; r < 4; ++r) {
            const int row0 = mg * 32 + lq * 4 + r;         // C/D row = lq*4 + r
            mv[row0][ng] = b0v[r]; m2l[row0][ng] = b02[r]; mi[row0][ng] = b0i[r];
            mv[row0 + 16][ng] = b1v[r]; m2l[row0 + 16][ng] = b12[r]; mi[row0 + 16][ng] = b1i[r];
        }
    }
    __syncthreads();

    // ---- merge ng halves per token; flag small margins (r8/r21-validated) ----
    if (tid < 64) {
        const float v0 = mv[tid][0], s0 = m2l[tid][0]; const int i0 = mi[tid][0];
        const float v1 = mv[tid][1], s1 = m2l[tid][1]; const int i1 = mi[tid][1];
        float fb, f2; int fi;
        if (v1 > v0 || (v1 == v0 && i1 < i0)) { fb = v1; fi = i1; f2 = fmaxf(v0, s1); }
        else { fb = v0; fi = i0; f2 = fmaxf(s0, v1); }
        idx_lds[tid] = fi;
        if (fb - f2 < TAU) { const int p = atomicAdd(&nflag, 1); flags[p] = tid; }
    }
    __syncthreads();

    // ---- inline rescue: exact fp32 recompute for flagged tokens (r21-validated) ----
    const int nf = nflag;
    for (int f = 0; f < nf; ++f) {
        const int wf = flags[f];
        xs[tid] = in[(size_t)(b * CC + tid) * HW + (size_t)h * WW + wf];
        __syncthreads();
        float best = -3.4e38f; int bidx = 0;
        #pragma unroll
        for (int cc = 0; cc < 4; ++cc) {
            const int code = tid * 4 + cc;                 // ascending per thread
            float sc = -eh_lds[code];
            const float* er = emb + (size_t)code * DD;
            for (int d = 0; d < DD; d += 4) {
                sc = fmaf(xs[d + 0], er[d + 0], sc);
                sc = fmaf(xs[d + 1], er[d + 1], sc);
                sc = fmaf(xs[d + 2], er[d + 2], sc);
                sc = fmaf(xs[d + 3], er[d + 3], sc);
            }
            if (sc > best) { best = sc; bidx = code; }
        }
        #pragma unroll
        for (int m2 = 1; m2 < 64; m2 <<= 1) {
            const float ov = __shfl_xor(best, m2, 64);
            const int   oi = __shfl_xor(bidx, m2, 64);
            if (ov > best || (ov == best && oi < bidx)) { best = ov; bidx = oi; }
        }
        if ((tid & 63) == 0) { rv[tid >> 6] = best; ri[tid >> 6] = bidx; }
        __syncthreads();
        if (tid == 0) {
            float fbv = rv[0]; int fbi = ri[0];
            #pragma unroll
            for (int q = 1; q < 4; ++q)
                if (rv[q] > fbv || (rv[q] == fbv && ri[q] < fbi)) { fbv = rv[q]; fbi = ri[q]; }
            idx_lds[wf] = fbi;
        }
        __syncthreads();
    }

    // ---- epilogue: out = x + (q - x), coalesced over w (r21-validated) ----
    {
        const int w = tid & 63, cs = tid >> 6;
        const float* srcx = in + (size_t)b * CC * HW + (size_t)h * WW + w;
        float* dst = out + (size_t)b * CC * HW + (size_t)h * WW + w;
        const float* erow = emb + (size_t)idx_lds[w] * DD;
        #pragma unroll
        for (int c = cs; c < CC; c += 4) {
            const float x = srcx[(size_t)c * HW];
            const float q = erow[c];
            dst[(size_t)c * HW] = x + (q - x);
        }
    }
}

// ---- fallback path (validated fp32 VALU kernel) if ws is too small ----
__global__ __launch_bounds__(256) void vq_enorm_kernel(const float* __restrict__ e,
                                                       float* __restrict__ ehalf) {
    const int wave = threadIdx.x >> 6;
    const int lane = threadIdx.x & 63;
    const int k = blockIdx.x * 4 + wave;
    const float4 v = *reinterpret_cast<const float4*>(e + (size_t)k * DD + lane * 4);
    float s = v.x * v.x + v.y * v.y + v.z * v.z + v.w * v.w;
    #pragma unroll
    for (int off = 32; off; off >>= 1) s += __shfl_xor(s, off, 64);
    if (lane == 0) ehalf[k] = 0.5f * s;
}

__global__ __launch_bounds__(256) void vq_fallback_kernel(
    const float* __restrict__ in, const float* __restrict__ emb,
    const float* __restrict__ ehalf, float* __restrict__ out) {

    __shared__ float x_lds[64][260];
    __shared__ float red_v[64][16];
    __shared__ int   red_i[64][16];
    __shared__ int   idx_lds[64];

    const int tid = threadIdx.x;
    const int bid = blockIdx.x;
    const int b = bid >> 6, h = bid & 63;
    const int w = tid & 63, cs = tid >> 6;
    {
        const float* src = in + (size_t)b * CC * HW + (size_t)h * WW + w;
        #pragma unroll
        for (int c = cs; c < CC; c += 4) x_lds[w][c] = src[(size_t)c * HW];
    }
    __syncthreads();
    const int i = tid & 15;
    const int j = tid >> 4;
    float best_v[4]; int best_i[4];
    #pragma unroll
    for (int t = 0; t < 4; ++t) { best_v[t] = -3.4e38f; best_i[t] = 0; }
    for (int chunk = 0; chunk < KK; chunk += 128) {
        const int c0 = chunk + j * 8;
        const float* e0 = emb + (size_t)c0 * DD;
        float acc[4][8];
        #pragma unroll
        for (int cj = 0; cj < 8; ++cj) {
            const float nh = -ehalf[c0 + cj];
            #pragma unroll
            for (int t = 0; t < 4; ++t) acc[t][cj] = nh;
        }
        #pragma unroll 2
        for (int d = 0; d < DD; d += 4) {
            float4 xv[4], ev[8];
            #pragma unroll
            for (int t = 0; t < 4; ++t)
                xv[t] = *reinterpret_cast<const float4*>(&x_lds[i + 16 * t][d]);
            #pragma unroll
            for (int cj = 0; cj < 8; ++cj)
                ev[cj] = *reinterpret_cast<const float4*>(e0 + (size_t)cj * DD + d);
            #pragma unroll
            for (int t = 0; t < 4; ++t) {
                #pragma unroll
                for (int cj = 0; cj < 8; ++cj) {
                    float a = acc[t][cj];
                    a = fmaf(xv[t].x, ev[cj].x, a);
                    a = fmaf(xv[t].y, ev[cj].y, a);
                    a = fmaf(xv[t].z, ev[cj].z, a);
                    a = fmaf(xv[t].w, ev[cj].w, a);
                    acc[t][cj] = a;
                }
            }
        }
        #pragma unroll
        for (int cj = 0; cj < 8; ++cj)
            #pragma unroll
            for (int t = 0; t < 4; ++t)
                if (acc[t][cj] > best_v[t]) { best_v[t] = acc[t][cj]; best_i[t] = c0 + cj; }
    }
    #pragma unroll
    for (int t = 0; t < 4; ++t) { red_v[i + 16 * t][j] = best_v[t]; red_i[i + 16 * t][j] = best_i[t]; }
    __syncthreads();
    if (tid < 64) {
        float bv = red_v[tid][0]; int bi = red_i[tid][0];
        #pragma unroll
        for (int jj = 1; jj < 16; ++jj) {
            const float v = red_v[tid][jj]; const int id = red_i[tid][jj];
            if (v > bv || (v == bv && id < bi)) { bv = v; bi = id; }
        }
        idx_lds[tid] = bi;
    }
    __syncthreads();
    {
        float* dst = out + (size_t)b * CC * HW + (size_t)h * WW + w;
        const float* erow = emb + (size_t)idx_lds[w] * DD;
        #pragma unroll
        for (int c = cs; c < CC; c += 4) {
            const float x = x_lds[w][c];
            const float q = erow[c];
            dst[(size_t)c * HW] = x + (q - x);
        }
    }
}

extern "C" void kernel_launch(void* const* d_in, const int* in_sizes, int n_in,
                              void* d_out, int out_size, void* d_ws, size_t ws_size,
                              hipStream_t stream) {
    const float* in  = (const float*)d_in[0];
    const float* emb = (const float*)d_in[1];
    float* out = (float*)d_out;
    char* ws = (char*)d_ws;

    float* ehalf = (float*)ws;                                 // 4 KiB
    const size_t OFF_EBT = 4096;
    const size_t NEED = OFF_EBT + (size_t)KK * DD * 2 * 2;     // + 1 MiB

    if (ws_size < NEED) {
        vq_enorm_kernel<<<KK / 4, 256, 0, stream>>>(emb, ehalf);
        vq_fallback_kernel<<<BB * HH, 256, 0, stream>>>(in, emb, ehalf, out);
        return;
    }
    uint4* ebt4 = (uint4*)(ws + OFF_EBT);

    vq_prep_kernel<<<32, 256, 0, stream>>>(emb, ehalf, ebt4);
    vq_mfma_kernel<<<BB * HH, 256, 0, stream>>>(in, emb, ehalf, ebt4, out);
}